// Round 4
// baseline (239.918 us; speedup 1.0000x reference)
//
#include <hip/hip_runtime.h>

typedef _Float16 h2 __attribute__((ext_vector_type(2)));

struct __align__(4) Px { h2 rg; h2 bq; float n; };  // 12 B: (r,g | b,q | n)

#define HH 480
#define WW 854
#define HWSZ (HH * WW)
#define PAD 192                 // = 3 * max dilation (64)
#define PSTR 1240               // padded row stride (>= 854 + 2*192 = 1238)
#define PH (HH + 2 * PAD)       // 864
#define PCELLS (PH * PSTR)      // 1,071,360 cells * 12 B = 12.86 MB

#if __has_builtin(__builtin_amdgcn_exp2f)
#define EXP2(x) __builtin_amdgcn_exp2f(x)
#else
#define EXP2(x) exp2f(x)
#endif

__device__ __forceinline__ float fdot2f(h2 a, h2 b, float c)
{
#if __has_builtin(__builtin_amdgcn_fdot2)
    return __builtin_amdgcn_fdot2(a, b, c, false);
#else
    return fmaf((float)a.x, (float)b.x, fmaf((float)a.y, (float)b.y, c));
#endif
}

// ---------------------------------------------------------------------------
// Sentinel fill: pad cells get n = 1e30 -> fma(n, nk<0, tp) ~ -7e29 -> e = 0.
// Written as 3 dwords per cell.
// ---------------------------------------------------------------------------
__global__ __launch_bounds__(256) void fill_sent(unsigned* __restrict__ W)
{
    int i = blockIdx.x * 256 + threadIdx.x;
    if (i < PCELLS * 3) W[i] = (i % 3 == 2) ? 0x7149F2CAu : 0u;  // 1e30f
}

// ---------------------------------------------------------------------------
// Pack P[p]: rgb rounded to f16 (pre-scaled by kernel-0 scales), q = softmax0,
// n = r^2+g^2+b^2 computed FROM THE ROUNDED values (matches diff arithmetic).
// ---------------------------------------------------------------------------
__global__ __launch_bounds__(256) void pack_q(
    const float* __restrict__ src, float scale,
    const float* __restrict__ xrgb, const float* __restrict__ fs,
    Px* __restrict__ P)
{
    int i = blockIdx.x * 256 + threadIdx.x;
    if (i >= HWSZ) return;
    float l0 = src[i], l1 = src[HWSZ + i];
    float q0 = 1.0f / (1.0f + __expf(scale * (l1 - l0)));
    _Float16 rh = (_Float16)(xrgb[i] * (1.0f / fs[2]));
    _Float16 gh = (_Float16)(xrgb[HWSZ + i] * (1.0f / fs[3]));
    _Float16 bh = (_Float16)(xrgb[2 * HWSZ + i] * (1.0f / fs[4]));
    float rf = (float)rh, gf = (float)gh, bf = (float)bh;
    Px v;
    v.rg = h2{rh, gh};
    v.bq = h2{bh, (_Float16)q0};
    v.n = fmaf(rf, rf, fmaf(gf, gf, bf * bf));
    int y = i / WW, x = i - y * WW;
    P[(y + PAD) * PSTR + x + PAD] = v;
}

// ---------------------------------------------------------------------------
// One tap (7 issue ops):
//   dot = rg_p.rg_q + b_p*b_q          (2x v_dot2_f32_f16, q masked out)
//   arg = tp' + nk*n_q - 2nk*dot       (2x fma; tp' has -C_k and log2 w folded)
//   e   = exp2(arg);  A += e*q;  B += e
// ---------------------------------------------------------------------------
__device__ __forceinline__ void tap(const Px aq, h2 rgp, h2 maskbp,
                                    float nk, float m2nk, float tpv,
                                    float& A, float& B)
{
    float s1 = fdot2f(rgp, aq.rg, 0.0f);
    float dot = fdot2f(maskbp, aq.bq, s1);
    float t = fmaf(aq.n, nk, tpv);
    float arg = fmaf(dot, m2nk, t);
    float e = EXP2(arg);
    A = fmaf(e, (float)aq.bq.y, A);   // q = hi half -> v_fma_mix
    B += e;
}

// One row of K taps at dilation DIL; loads batched first for ILP.
template <int K, int DIL>
__device__ __forceinline__ void row_taps(const Px* __restrict__ rp,
                                         const float* __restrict__ tr,
                                         h2 rgp, h2 maskbp,
                                         float nk, float m2nk,
                                         float& A, float& B)
{
    Px buf[K];
#pragma unroll
    for (int j = 0; j < K; ++j) buf[j] = rp[(j - K / 2) * DIL];
#pragma unroll
    for (int j = 0; j < K; ++j)
        tap(buf[j], rgp, maskbp, nk, m2nk, tr[j], A, B);
}

// ---------------------------------------------------------------------------
// Fused 3-kernel message passing + compat + logQ update.  Block = 128x2.
// ---------------------------------------------------------------------------
__global__ __launch_bounds__(256) void crf_step(
    const Px* __restrict__ P, const float* __restrict__ unary,
    const float* __restrict__ fs, const float* __restrict__ uwArr,
    const float* __restrict__ pwArr,
    const float* __restrict__ w0, const float* __restrict__ w1,
    const float* __restrict__ w2,
    const float* __restrict__ c0, const float* __restrict__ c1,
    int step, float* __restrict__ out)
{
    __shared__ __align__(16) float tp0[7 * 8];
    __shared__ __align__(16) float tp1[7 * 8];
    __shared__ __align__(16) float tp2[9 * 12];
    __shared__ float scal[21];

    const float NH = -0.72134752044448169f;  // -0.5 * log2(e)
    int tid = threadIdx.y * 128 + threadIdx.x;

    // n_max in kernel-0 scale (rgb in [0,255] pre-scaled by 1/fs[2..4])
    float i2 = 255.0f / fs[2], i3 = 255.0f / fs[3], i4 = 255.0f / fs[4];
    float nmax = i2 * i2 + i3 * i3 + i4 * i4;

    if (tid < 49) {                       // kernel 0: 7x7 dil 64
        float C = -0.5f * NH * nmax;
        int dy = tid / 7 - 3, dx = tid % 7 - 3;
        float py = dy * 64.0f / fs[0], px = dx * 64.0f / fs[1];
        tp0[(tid / 7) * 8 + tid % 7] =
            log2f(w0[step * 49 + tid]) + NH * (py * py + px * px) - C;
    } else if (tid >= 64 && tid < 113) {  // kernel 1: 7x7 dil 16
        int t = tid - 64;
        float r1 = fs[2] / fs[7];
        float C = -0.5f * NH * r1 * r1 * nmax;
        int dy = t / 7 - 3, dx = t % 7 - 3;
        float py = dy * 16.0f / fs[5], px = dx * 16.0f / fs[6];
        tp1[(t / 7) * 8 + t % 7] =
            log2f(w1[step * 49 + t]) + NH * (py * py + px * px) - C;
    } else if (tid >= 128 && tid < 209) { // kernel 2: 9x9 dil 1
        int t = tid - 128;
        float r2 = fs[2] / fs[12];
        float C = -0.5f * NH * r2 * r2 * nmax;
        int dy = t / 9 - 4, dx = t % 9 - 4;
        float py = dy / fs[10], px = dx / fs[11];
        tp2[(t / 9) * 12 + t % 9] =
            log2f(w2[step * 81 + t]) + NH * (py * py + px * px) - C;
    } else if (tid == 224) {
        float r1 = fs[2] / fs[7], r2 = fs[2] / fs[12];
        float nk0 = NH, nk1 = NH * r1 * r1, nk2 = NH * r2 * r2;
        scal[0] = nk0; scal[1] = nk1; scal[2] = nk2;
        scal[3] = -2.0f * nk0; scal[4] = -2.0f * nk1; scal[5] = -2.0f * nk2;
        scal[6] = -0.5f * nk0 * nmax;   // C0
        scal[7] = -0.5f * nk1 * nmax;   // C1
        scal[8] = -0.5f * nk2 * nmax;   // C2
        scal[9]  = c0[step * 4 + 0];  scal[10] = c0[step * 4 + 1];
        scal[11] = c0[step * 4 + 2];  scal[12] = c0[step * 4 + 3];
        scal[13] = c1[step * 4 + 0];  scal[14] = c1[step * 4 + 1];
        scal[15] = c1[step * 4 + 2];  scal[16] = c1[step * 4 + 3];
        scal[17] = pwArr[step * 3 + 0];
        scal[18] = pwArr[step * 3 + 1];
        scal[19] = pwArr[step * 3 + 2];
        scal[20] = uwArr[step] * 5.0f;
    }
    __syncthreads();

    int x = blockIdx.x * 128 + threadIdx.x;
    int y = blockIdx.y * 2 + threadIdx.y;
    if (x >= WW) return;
    int p = y * WW + x;

    const Px* Pc = P + (y + PAD) * PSTR + (x + PAD);
    Px cp = *Pc;
    h2 rgp = cp.rg;
    union { h2 h; unsigned u; } ub;
    ub.h = cp.bq; ub.u &= 0xFFFFu;      // (b_p, 0) masks q out of the dot
    h2 maskbp = ub.h;
    float np = cp.n;

    float nk0 = scal[0], nk1 = scal[1], nk2 = scal[2];
    float m0 = scal[3], m1 = scal[4], m2 = scal[5];

    float A0 = 0.f, B0 = 0.f, A1 = 0.f, B1 = 0.f, A2 = 0.f, B2 = 0.f;

#pragma unroll
    for (int i = 0; i < 9; ++i) {
        if (i < 7) {
            row_taps<7, 64>(Pc + (i - 3) * 64 * PSTR, tp0 + i * 8,
                            rgp, maskbp, nk0, m0, A0, B0);
            row_taps<7, 16>(Pc + (i - 3) * 16 * PSTR, tp1 + i * 8,
                            rgp, maskbp, nk1, m1, A1, B1);
        }
        row_taps<9, 1>(Pc + (i - 4) * PSTR, tp2 + i * 12,
                       rgp, maskbp, nk2, m2, A2, B2);
    }

    // undo the per-center bias: true message = acc * 2^(nk*n_p + C)
    float f0 = EXP2(fmaf(nk0, np, scal[6]));
    float f1 = EXP2(fmaf(nk1, np, scal[7]));
    float f2 = EXP2(fmaf(nk2, np, scal[8]));
    A0 *= f0; B0 *= f0;
    A1 *= f1; B1 *= f1;
    A2 *= f2; B2 *= f2;

    float m00 = A0, m01 = B0 - A0;
    float m10 = A1, m11 = B1 - A1;
    float m20 = A2, m21 = B2 - A2;

    float r00 = scal[9]  * m00 + scal[10] * m01;
    float r01 = scal[11] * m00 + scal[12] * m01;
    float r10 = scal[13] * m10 + scal[14] * m11;
    float r11 = scal[15] * m10 + scal[16] * m11;

    float pw0 = scal[17], pw1 = scal[18], pw2 = scal[19], uw5 = scal[20];
    float o0 = uw5 * unary[p] + pw0 * r00 + pw1 * r10 + pw2 * m20;
    float o1 = uw5 * unary[HWSZ + p] + pw0 * r01 + pw1 * r11 + pw2 * m21;
    out[p] = o0;
    out[HWSZ + p] = o1;
}

// ---------------------------------------------------------------------------
extern "C" void kernel_launch(void* const* d_in, const int* in_sizes, int n_in,
                              void* d_out, int out_size, void* d_ws, size_t ws_size,
                              hipStream_t stream)
{
    const float* unary = (const float*)d_in[0];
    const float* xrgb  = (const float*)d_in[1];
    const float* fs    = (const float*)d_in[2];
    // d_in[3] = potts_w (dead in reference forward)
    const float* uw    = (const float*)d_in[4];
    const float* pw    = (const float*)d_in[5];
    const float* w0    = (const float*)d_in[6];
    const float* w1    = (const float*)d_in[7];
    const float* w2    = (const float*)d_in[8];
    const float* c0    = (const float*)d_in[9];
    const float* c1    = (const float*)d_in[10];
    float* out = (float*)d_out;
    Px* P = (Px*)d_ws;  // 12.86 MB padded sentinel array

    fill_sent<<<(PCELLS * 3 + 255) / 256, 256, 0, stream>>>((unsigned*)d_ws);

    dim3 gs((WW + 127) / 128, HH / 2), bs(128, 2);
    int packBlocks = (HWSZ + 255) / 256;

    for (int s = 0; s < 5; ++s) {
        const float* src = (s == 0) ? unary : out;
        float scale = (s == 0) ? 5.0f : 1.0f;
        pack_q<<<packBlocks, 256, 0, stream>>>(src, scale, xrgb, fs, P);
        crf_step<<<gs, bs, 0, stream>>>(P, unary, fs, uw, pw, w0, w1, w2,
                                        c0, c1, s, out);
    }
}